// Round 6
// baseline (238.698 us; speedup 1.0000x reference)
//
#include <hip/hip_runtime.h>
#include <cstdint>
#include <cstddef>

typedef __bf16 bf16;
typedef __attribute__((ext_vector_type(8))) __bf16 bf16x8;
typedef __attribute__((ext_vector_type(4))) __bf16 bf16x4;
typedef __attribute__((ext_vector_type(4))) float f32x4;
typedef __attribute__((ext_vector_type(4))) short s16x4;

#define S_LEN   2048
#define WIN     512
#define NH_Q    16
#define NH_KV   4
#define HD_     128
#define NTOK    4096   // B * S

// Q is pre-scaled by (1/sqrt(128)) * log2(e) at the QKV epilogue, so attn
// uses exp2 directly and needs no per-score scale multiply.
#define QSCALE_LOG2E 0.12751744561823337f

#if defined(__has_builtin)
#if __has_builtin(__builtin_amdgcn_mfma_f32_16x16x16bf16_1k)
#define HAVE_MFMA16 1
#endif
#endif
#ifndef HAVE_MFMA16
#define HAVE_MFMA16 0
#endif

// s_waitcnt immediates (gfx9 encoding: vm[3:0]=s[3:0], exp=s[6:4],
// lgkm=s[11:8], vm[5:4]=s[15:14]); non-waited fields all-ones.
#define WAIT_VM8   0x0F78  // vmcnt<=8
#define WAIT_VM6   0x0F76  // vmcnt<=6
#define WAIT_VM4   0x0F74  // vmcnt<=4
#define WAIT_VM3   0x0F73  // vmcnt<=3
#define WAIT_VM2   0x0F72  // vmcnt<=2
#define WAIT_VM0   0x0F70  // vmcnt<=0
#define WAIT_L0    0xC07F  // lgkmcnt<=0
#define CFENCE() __asm__ __volatile__("" ::: "memory")

// async global->LDS, 16B per lane; LDS dest = wave-uniform base + lane*16
__device__ __forceinline__ void async_copy16(const void* g, void* l) {
  __builtin_amdgcn_global_load_lds(
      (const __attribute__((address_space(1))) void*)g,
      (__attribute__((address_space(3))) void*)l, 16, 0, 0);
}

// ---------------- fp32 -> bf16 convert, all 5 arrays in one launch ----------
__global__ __launch_bounds__(256)
void cvt_all(const float* __restrict__ hs, const float* __restrict__ wq,
             const float* __restrict__ wk, const float* __restrict__ wv,
             const float* __restrict__ wo, bf16* __restrict__ hsb,
             bf16* __restrict__ wqb, bf16* __restrict__ wkb,
             bf16* __restrict__ wvb, bf16* __restrict__ wob) {
  long i = ((long)blockIdx.x * 256 + threadIdx.x) * 4;  // < 18874368
  const float* in;
  bf16* out;
  if (i < 8388608)       { in = hs + i;            out = hsb + i; }
  else if (i < 12582912) { in = wq + (i - 8388608); out = wqb + (i - 8388608); }
  else if (i < 13631488) { in = wk + (i - 12582912); out = wkb + (i - 12582912); }
  else if (i < 14680064) { in = wv + (i - 13631488); out = wvb + (i - 13631488); }
  else                   { in = wo + (i - 14680064); out = wob + (i - 14680064); }
  float4 v = *(const float4*)in;
  bf16x4 t = {(bf16)v.x, (bf16)v.y, (bf16)v.z, (bf16)v.w};
  *(bf16x4*)out = t;
}

// ---------------- output GEMM: 256x128 tile, 4-phase schedule, 1 block/CU ---
__global__ __launch_bounds__(512, 2)
void gemm_out8(const bf16* __restrict__ A, const bf16* __restrict__ W,
               float* __restrict__ C) {
  __shared__ __align__(16) char smem[98304];  // A[2]: 0/32K, B[2]: 64K/80K
  const int tid  = threadIdx.x;
  const int wave = tid >> 6, lane = tid & 63;
  const int quad = lane >> 4, l16 = lane & 15;
  const int wm = wave >> 1, wn = wave & 1;   // 4x2 wave grid, 64x64 each

  // XCD-swizzled tile coords (grid 16(n) x 16(m) = 256 = 8 XCD x 32)
  const int flat = blockIdx.y * 16 + blockIdx.x;
  const int swz  = (flat & 7) * 32 + (flat >> 3);
  const int m0 = (swz >> 4) * 256;
  const int n0 = (swz & 15) * 128;

  // swizzled within-subtile read byte offset (st_16x32, R6-verified)
  const int rdb = (l16 * 64 + quad * 16) ^ ((l16 & 8) << 2);
  const int srow = lane >> 2;
  const int scol = ((lane & 3) * 8) ^ ((lane >> 5) << 4);

  const bf16* aptr[2][2];
  int adst[2][2];
#pragma unroll
  for (int mh = 0; mh < 2; ++mh)
#pragma unroll
    for (int j = 0; j < 2; ++j) {
      const int rb = (wave >> 1) * 4 + mh * 2 + j;
      aptr[mh][j] = A + (size_t)(m0 + rb * 16 + srow) * 2048 + scol
                    + (wave & 1) * 32;
      adst[mh][j] = (rb * 2 + (wave & 1)) << 10;
    }
  const bf16* bptr[2];
  int bdst[2];
#pragma unroll
  for (int nh = 0; nh < 2; ++nh) {
    const int cb = (wave >> 2) * 4 + nh * 2 + ((wave >> 1) & 1);
    bptr[nh] = W + (size_t)(n0 + cb * 16 + srow) * 2048 + scol
               + (wave & 1) * 32;
    bdst[nh] = (cb * 2 + (wave & 1)) << 10;
  }

#define STAGE_A(mh, tt) do { char* _b = smem + ((tt) & 1) * 32768;      \
    async_copy16(aptr[mh][0] + (tt) * 64, _b + adst[mh][0]);            \
    async_copy16(aptr[mh][1] + (tt) * 64, _b + adst[mh][1]); } while (0)
#define STAGE_B(nh, tt) do { char* _b = smem + 65536 + ((tt) & 1) * 16384; \
    async_copy16(bptr[nh] + (tt) * 64, _b + bdst[nh]); } while (0)

  f32x4 acc[4][4];
#pragma unroll
  for (int i = 0; i < 4; ++i)
#pragma unroll
    for (int j = 0; j < 4; ++j) acc[i][j] = (f32x4){0.f, 0.f, 0.f, 0.f};

  bf16x8 afr[2][2];
  bf16x8 bfr[2][2][2];

  auto read_a = [&](const char* Ab, int mh) __attribute__((always_inline)) {
#pragma unroll
    for (int mt2 = 0; mt2 < 2; ++mt2)
#pragma unroll
      for (int ks = 0; ks < 2; ++ks)
        afr[mt2][ks] = *(const bf16x8*)(
            Ab + (((wm * 4 + mh * 2 + mt2) * 2 + ks) << 10) + rdb);
  };
  auto read_b = [&](const char* Bb, int nh) __attribute__((always_inline)) {
#pragma unroll
    for (int nt2 = 0; nt2 < 2; ++nt2)
#pragma unroll
      for (int ks = 0; ks < 2; ++ks)
        bfr[nh][nt2][ks] = *(const bf16x8*)(
            Bb + (((wn * 4 + nh * 2 + nt2) * 2 + ks) << 10) + rdb);
  };
  auto do_mfma = [&](int mh, int nh) __attribute__((always_inline)) {
    __builtin_amdgcn_s_setprio(1);
#pragma unroll
    for (int mt2 = 0; mt2 < 2; ++mt2)
#pragma unroll
      for (int nt2 = 0; nt2 < 2; ++nt2)
#pragma unroll
        for (int ks = 0; ks < 2; ++ks)
          acc[mh * 2 + mt2][nh * 2 + nt2] = __builtin_amdgcn_mfma_f32_16x16x32_bf16(
              afr[mt2][ks], bfr[nh][nt2][ks], acc[mh * 2 + mt2][nh * 2 + nt2],
              0, 0, 0);
    __builtin_amdgcn_s_setprio(0);
  };

  STAGE_A(0, 0); STAGE_B(0, 0); STAGE_B(1, 0); STAGE_A(1, 0);
  CFENCE();

  for (int t = 0; t < 31; ++t) {
    const char* Ab = smem + (t & 1) * 32768;
    const char* Bb = smem + 65536 + (t & 1) * 16384;
    const int nx = t + 1;
    __builtin_amdgcn_s_waitcnt(WAIT_VM3); CFENCE();
    __builtin_amdgcn_s_barrier(); CFENCE();
    read_a(Ab, 0); read_b(Bb, 0);
    STAGE_A(0, nx); CFENCE();
    do_mfma(0, 0);
    __builtin_amdgcn_s_waitcnt(WAIT_VM4); CFENCE();
    __builtin_amdgcn_s_barrier(); CFENCE();
    read_b(Bb, 1);
    STAGE_B(0, nx); CFENCE();
    do_mfma(0, 1);
    __builtin_amdgcn_s_waitcnt(WAIT_VM3); CFENCE();
    __builtin_amdgcn_s_barrier(); CFENCE();
    read_a(Ab, 1);
    STAGE_B(1, nx); CFENCE();
    do_mfma(1, 0);
    __builtin_amdgcn_s_barrier(); CFENCE();
    STAGE_A(1, nx); CFENCE();
    do_mfma(1, 1);
  }
  {
    const char* Ab = smem + 32768;
    const char* Bb = smem + 65536 + 16384;
    __builtin_amdgcn_s_waitcnt(WAIT_VM3); CFENCE();
    __builtin_amdgcn_s_barrier(); CFENCE();
    read_a(Ab, 0); read_b(Bb, 0);
    do_mfma(0, 0);
    __builtin_amdgcn_s_waitcnt(WAIT_VM2); CFENCE();
    __builtin_amdgcn_s_barrier(); CFENCE();
    read_b(Bb, 1);
    do_mfma(0, 1);
    __builtin_amdgcn_s_waitcnt(WAIT_VM0); CFENCE();
    __builtin_amdgcn_s_barrier(); CFENCE();
    read_a(Ab, 1);
    do_mfma(1, 0);
    do_mfma(1, 1);
  }
#undef STAGE_A
#undef STAGE_B

#pragma unroll
  for (int mt = 0; mt < 4; ++mt)
#pragma unroll
    for (int nt = 0; nt < 4; ++nt)
#pragma unroll
      for (int r = 0; r < 4; ++r) {
        const int row = m0 + wm * 64 + mt * 16 + quad * 4 + r;
        const int col = n0 + wn * 64 + nt * 16 + l16;
        C[(size_t)row * 2048 + col] = acc[mt][nt][r];
      }
}

// ---------------- fused QKV GEMM v11: BK=32, 4-slot ring, deep prefetch -----
// R5 counters (qkv10): 53.5us, MfmaUtil 37.7 -- read-early/counted-lgkm was
// NEUTRAL, so the stall is not LDS-read latency. Revised model: shallow
// (<1-tile) prefetch exposes HBM latency at the per-tile vmcnt waits, and
// staging+reads only partially overlap MFMA. m201-proven fix: 3 K-tiles in
// flight. BK=32, 4-slot LDS ring (4 x (16KB A + 12KB B) = 112KB). Per K-step
// 2 phases x 12 MFMA: {ds_read frags -> stage t+3 -> barrier -> lgkm(0)+
// sched_barrier -> MFMA}. Reads issue BEFORE the barrier (latency hides in
// barrier wait). Per-wave stage units: waves 0-3 = 4 (2A+2B), waves 4-7 = 3
// (2A+1B); counted wait once per K-step = "tile t+1 landed" = vm(2u_w)
// (vm8/vm6, wave-uniform branch), placed before the Ph2 barrier ->
// collective confirmation for Ph1(t+1) reads. Never vm0 until 3-tile peel.
// Slot written at Ph1(t) = slot[(t-1)&3], whose last reads drained at
// Ph2(t-1)'s lgkm(0) before the intervening barrier -> no write hazard.
__global__ __launch_bounds__(512, 2)
void gemm_qkv11(const bf16* __restrict__ A, const bf16* __restrict__ Wq,
                const bf16* __restrict__ Wk, const bf16* __restrict__ Wv,
                bf16* __restrict__ Qo, bf16* __restrict__ Ko,
                bf16* __restrict__ Vt) {
  __shared__ __align__(16) char smem[114688];  // A ring 4x16K @0, B ring 4x12K @64K
  const int tid  = threadIdx.x;
  const int wave = tid >> 6, lane = tid & 63;
  const int quad = lane >> 4, l16 = lane & 15;
  const int wm = wave >> 1, wn = wave & 1;   // 4x2 wave grid, 64 rows x 96 cols

  const int flat = blockIdx.y * 16 + blockIdx.x;
  const int swz  = (flat & 7) * 32 + (flat >> 3);
  const int m0 = (swz >> 4) * 256;
  const int n0 = (swz & 15) * 192;

  // swizzled within-subtile read byte offset (st_16x32, verified)
  const int rdb = (l16 * 64 + quad * 16) ^ ((l16 & 8) << 2);
  const int srow = lane >> 2;
  const int scol = ((lane & 3) * 8) ^ ((lane >> 5) << 4);

  // A: 16 units/tile (16 rows x 32 cols each), 2 per wave: uA = wave*2 + i.
  const bf16* aup[2];
  int adst[2];
#pragma unroll
  for (int i = 0; i < 2; ++i) {
    const int uA = wave * 2 + i;
    aup[i]  = A + (size_t)(m0 + uA * 16 + srow) * 2048 + scol;
    adst[i] = uA << 10;
  }
  // B: 12 units/tile; waves 0-3 own {2w, 2w+1}, waves 4-7 own {4+w}.
  const int uB0 = (wave < 4) ? wave * 2 : 4 + wave;
  const int uB1 = wave * 2 + 1;  // valid only for wave<4
  const int nrow0 = n0 + uB0 * 16 + srow;
  const int nrow1 = n0 + uB1 * 16 + srow;
  const bf16* bup0 = (nrow0 < 2048 ? Wq + (size_t)nrow0 * 2048
                    : nrow0 < 2560 ? Wk + (size_t)(nrow0 - 2048) * 2048
                                   : Wv + (size_t)(nrow0 - 2560) * 2048) + scol;
  const bf16* bup1 = (nrow1 < 2048 ? Wq + (size_t)nrow1 * 2048
                    : nrow1 < 2560 ? Wk + (size_t)(nrow1 - 2048) * 2048
                                   : Wv + (size_t)(nrow1 - 2560) * 2048) + scol;
  const int bdst0 = uB0 << 10;
  const int bdst1 = uB1 << 10;

  auto stageA = [&](int tt) __attribute__((always_inline)) {
    char* _b = smem + (tt & 3) * 16384;
    async_copy16(aup[0] + (size_t)tt * 32, _b + adst[0]);
    async_copy16(aup[1] + (size_t)tt * 32, _b + adst[1]);
  };
  auto stageB = [&](int tt) __attribute__((always_inline)) {
    char* _b = smem + 65536 + (tt & 3) * 12288;
    async_copy16(bup0 + (size_t)tt * 32, _b + bdst0);
    if (wave < 4) async_copy16(bup1 + (size_t)tt * 32, _b + bdst1);
  };

  f32x4 acc[4][6];
#pragma unroll
  for (int i = 0; i < 4; ++i)
#pragma unroll
    for (int j = 0; j < 6; ++j) acc[i][j] = (f32x4){0.f, 0.f, 0.f, 0.f};

  bf16x8 afr[2], afr2[2];  // A frags for mh0 (rows 0-31) and mh1 (32-63)
  bf16x8 bfr[6];           // all 6 interleaved n-chunks (k=32 whole)

  auto read_ph1 = [&](int t) __attribute__((always_inline)) {
    const char* sA = smem + (t & 3) * 16384;
    const char* sB = smem + 65536 + (t & 3) * 12288;
#pragma unroll
    for (int mt2 = 0; mt2 < 2; ++mt2)
      afr[mt2] = *(const bf16x8*)(sA + ((wm * 4 + mt2) << 10) + rdb);
#pragma unroll
    for (int j = 0; j < 6; ++j) {
      const int cc = (j >> 1) * 4 + (j & 1) * 2 + wn;
      bfr[j] = *(const bf16x8*)(sB + (cc << 10) + rdb);
    }
  };
  auto read_ph2 = [&](int t) __attribute__((always_inline)) {
    const char* sA = smem + (t & 3) * 16384;
#pragma unroll
    for (int mt2 = 0; mt2 < 2; ++mt2)
      afr2[mt2] = *(const bf16x8*)(sA + ((wm * 4 + 2 + mt2) << 10) + rdb);
  };
  auto mfma_ph1 = [&]() __attribute__((always_inline)) {
    __builtin_amdgcn_s_setprio(1);
#pragma unroll
    for (int mt2 = 0; mt2 < 2; ++mt2)
#pragma unroll
      for (int j = 0; j < 6; ++j)
        acc[mt2][j] = __builtin_amdgcn_mfma_f32_16x16x32_bf16(
            afr[mt2], bfr[j], acc[mt2][j], 0, 0, 0);
    __builtin_amdgcn_s_setprio(0);
  };
  auto mfma_ph2 = [&]() __attribute__((always_inline)) {
    __builtin_amdgcn_s_setprio(1);
#pragma unroll
    for (int mt2 = 0; mt2 < 2; ++mt2)
#pragma unroll
      for (int j = 0; j < 6; ++j)
        acc[2 + mt2][j] = __builtin_amdgcn_mfma_f32_16x16x32_bf16(
            afr2[mt2], bfr[j], acc[2 + mt2][j], 0, 0, 0);
    __builtin_amdgcn_s_setprio(0);
  };

  // prologue: stage tiles 0,1,2 (tile-monotone per wave); wait tile 0 landed.
  stageA(0); stageB(0);
  stageA(1); stageB(1);
  stageA(2); stageB(2);
  CFENCE();
  if (wave < 4) __builtin_amdgcn_s_waitcnt(WAIT_VM8);
  else          __builtin_amdgcn_s_waitcnt(WAIT_VM6);
  CFENCE();
  __builtin_amdgcn_s_barrier(); CFENCE();

  for (int t = 0; t < 61; ++t) {
    // Ph1: reads (slot t confirmed at prev Ph2 barrier) -> stage A(t+3)
    read_ph1(t);
    stageA(t + 3);
    CFENCE();
    __builtin_amdgcn_s_barrier(); CFENCE();
    __builtin_amdgcn_s_waitcnt(WAIT_L0);
    __builtin_amdgcn_sched_barrier(0);
    mfma_ph1();
    // Ph2: reads A1 -> stage B(t+3) -> counted vm (tile t+1 landed) -> barrier
    read_ph2(t);
    stageB(t + 3);
    CFENCE();
    if (wave < 4) __builtin_amdgcn_s_waitcnt(WAIT_VM8);
    else          __builtin_amdgcn_s_waitcnt(WAIT_VM6);
    CFENCE();
    __builtin_amdgcn_s_barrier(); CFENCE();
    __builtin_amdgcn_s_waitcnt(WAIT_L0);
    __builtin_amdgcn_sched_barrier(0);
    mfma_ph2();
  }
  // peeled tail: tiles 61, 62, 63 (no staging; drain 2u -> u -> 0)
  {
    // t = 61: need tile 62 landed -> vm(u)
    read_ph1(61); CFENCE();
    __builtin_amdgcn_s_barrier(); CFENCE();
    __builtin_amdgcn_s_waitcnt(WAIT_L0);
    __builtin_amdgcn_sched_barrier(0);
    mfma_ph1();
    read_ph2(61); CFENCE();
    if (wave < 4) __builtin_amdgcn_s_waitcnt(WAIT_VM4);
    else          __builtin_amdgcn_s_waitcnt(WAIT_VM3);
    CFENCE();
    __builtin_amdgcn_s_barrier(); CFENCE();
    __builtin_amdgcn_s_waitcnt(WAIT_L0);
    __builtin_amdgcn_sched_barrier(0);
    mfma_ph2();
    // t = 62: need tile 63 landed -> vm(0)
    read_ph1(62); CFENCE();
    __builtin_amdgcn_s_barrier(); CFENCE();
    __builtin_amdgcn_s_waitcnt(WAIT_L0);
    __builtin_amdgcn_sched_barrier(0);
    mfma_ph1();
    read_ph2(62); CFENCE();
    __builtin_amdgcn_s_waitcnt(WAIT_VM0); CFENCE();
    __builtin_amdgcn_s_barrier(); CFENCE();
    __builtin_amdgcn_s_waitcnt(WAIT_L0);
    __builtin_amdgcn_sched_barrier(0);
    mfma_ph2();
    // t = 63: everything resident
    read_ph1(63); CFENCE();
    __builtin_amdgcn_s_barrier(); CFENCE();
    __builtin_amdgcn_s_waitcnt(WAIT_L0);
    __builtin_amdgcn_sched_barrier(0);
    mfma_ph1();
    read_ph2(63); CFENCE();
    __builtin_amdgcn_s_waitcnt(WAIT_L0);
    __builtin_amdgcn_sched_barrier(0);
    mfma_ph2();
  }

  // epilogue: RoPE on rotary 64-blocks (cb ≡ 0 mod 128, cb < 2560).
  // frag 2b holds col cb + d, frag 2b+1 holds col cb + d + 32, d = wn*16+l16.
  {
    const float d = (float)(wn * 16 + l16);
    const float invf = exp2f(-d * 0.41524101186091903f);  // 1e4^(-d/32)
#pragma unroll
    for (int b = 0; b < 3; ++b) {
      const int cb = n0 + b * 64;
      if (cb < 2560 && (cb & 127) == 0) {
#pragma unroll
        for (int mt = 0; mt < 4; ++mt)
#pragma unroll
          for (int r = 0; r < 4; ++r) {
            const int pos = (m0 + wm * 64 + mt * 16 + quad * 4 + r) & (S_LEN - 1);
            float s, c;
            __sincosf((float)pos * invf, &s, &c);
            const float x1 = acc[mt][2 * b][r], x2 = acc[mt][2 * b + 1][r];
            acc[mt][2 * b][r]     = x1 * c - x2 * s;
            acc[mt][2 * b + 1][r] = x2 * c + x1 * s;
          }
      }
    }
  }
#pragma unroll
  for (int mt = 0; mt < 4; ++mt) {
    const int row0 = m0 + wm * 64 + mt * 16 + quad * 4;
#pragma unroll
    for (int j = 0; j < 6; ++j) {
      const int col16 = n0 + (j >> 1) * 64 + ((j & 1) * 2 + wn) * 16;
      if (col16 < 2048) {                 // Q: [tok][2048], pre-scaled
#pragma unroll
        for (int r = 0; r < 4; ++r)
          Qo[(size_t)(row0 + r) * 2048 + col16 + l16] =
              (bf16)(acc[mt][j][r] * QSCALE_LOG2E);
      } else if (col16 < 2560) {          // K: [tok][512]
#pragma unroll
        for (int r = 0; r < 4; ++r)
          Ko[(size_t)(row0 + r) * 512 + col16 - 2048 + l16] = (bf16)acc[mt][j][r];
      } else {                            // V: transposed vt[(b*4+kv)*128+d][s]
        const int colv = col16 + l16 - 2560;
        const int bb = row0 >> 11, s0 = row0 & (S_LEN - 1);
        bf16x4 tq = {(bf16)acc[mt][j][0], (bf16)acc[mt][j][1],
                     (bf16)acc[mt][j][2], (bf16)acc[mt][j][3]};
        *(bf16x4*)(Vt + ((size_t)(bb * NH_KV + (colv >> 7)) * HD_ + (colv & 127))
                        * S_LEN + s0) = tq;
      }
    }
  }
}

// ---------------- flash attention v2: 128-query blocks, 8 waves -------------
#define KS_STRIDE 136   // 64 keys x 128 d (+pad)
#define VT_STRIDE 72    // 128 d x 64 keys (+pad)

__global__ __launch_bounds__(512, 4)
void attn_kernel(const bf16* __restrict__ Qg, const bf16* __restrict__ Kg,
                 const bf16* __restrict__ Vtg, bf16* __restrict__ Og) {
  __shared__ __align__(16) char smem_raw[35840];
  bf16* const Ks = (bf16*)smem_raw;                // [64][KS_STRIDE]
  bf16* const Vt = (bf16*)(smem_raw + 17408);      // [128][VT_STRIDE]
  bf16* const Os = (bf16*)smem_raw;                // [128][KS_STRIDE] (output)

  const int tid  = threadIdx.x;
  const int wave = tid >> 6, lane = tid & 63;
  const int quad = lane >> 4, l16 = lane & 15;

  // T1: XCD swizzle over 512 blocks = 8 XCD x 64.
  const int flat = blockIdx.x + 16 * blockIdx.y + 256 * blockIdx.z;
  const int swz  = (flat & 7) * 64 + (flat >> 3);
  const int qt = swz & 15, h = (swz >> 4) & 15, b = swz >> 8;

  const int kv = h >> 2;
  const int q0 = qt * 128;
  const int tok0 = b * S_LEN;
  const int qw = q0 + wave * 16;       // wave's first q-row
  const int q  = qw + l16;             // this thread's q-row

  bf16x8 qf[4];
  {
    const bf16* qp = Qg + (size_t)(tok0 + q) * (NH_Q * HD_) + h * HD_ + quad * 8;
#pragma unroll
    for (int kb = 0; kb < 4; ++kb) qf[kb] = *(const bf16x8*)(qp + kb * 32);
  }

  f32x4 o[8];
#pragma unroll
  for (int dt = 0; dt < 8; ++dt) o[dt] = (f32x4){0.f, 0.f, 0.f, 0.f};
  float m_run = -__builtin_inff(), l_run = 0.f;

  int kt_begin = q0 - WIN;
  if (kt_begin < 0) kt_begin = 0;
  const int kt_end = q0 + 128;
  const bf16* kg_base = Kg + (size_t)tok0 * (NH_KV * HD_) + kv * HD_;
  const bf16* vt_base = Vtg + (size_t)(b * NH_KV + kv) * HD_ * S_LEN;

  // staging thread constants (512 threads, 2 chunks each for K and V)
  const int skey = tid >> 4, sdbl = tid & 15;   // K: rows skey, skey+32
  const int svd  = tid >> 3, skb  = tid & 7;    // V: rows svd, svd+64

  bf16x8 pk0, pk1, pv0, pv1;  // T14 prefetch registers
  auto PF = [&](int kt) __attribute__((always_inline)) {
    pk0 = *(const bf16x8*)(kg_base + (size_t)(kt + skey) * (NH_KV * HD_) + sdbl * 8);
    pk1 = *(const bf16x8*)(kg_base + (size_t)(kt + skey + 32) * (NH_KV * HD_) + sdbl * 8);
    pv0 = *(const bf16x8*)(vt_base + (size_t)svd * S_LEN + kt + skb * 8);
    pv1 = *(const bf16x8*)(vt_base + (size_t)(svd + 64) * S_LEN + kt + skb * 8);
  };
  auto WR = [&]() __attribute__((always_inline)) {
    *(bf16x8*)&Ks[skey * KS_STRIDE + sdbl * 8] = pk0;
    *(bf16x8*)&Ks[(skey + 32) * KS_STRIDE + sdbl * 8] = pk1;
    *(bf16x8*)&Vt[svd * VT_STRIDE + skb * 8] = pv0;
    *(bf16x8*)&Vt[(svd + 64) * VT_STRIDE + skb * 8] = pv1;
  };

  PF(kt_begin);
  for (int kt = kt_begin; kt < kt_end; kt += 64) {
    __syncthreads();                 // previous tile's consumers done
    WR();                            // (compiler waits the PF loads)
    __syncthreads();
    if (kt + 64 < kt_end) PF(kt + 64);  // overlap next loads with compute

    // wave-uniform tile classification
    const bool active = (kt <= qw + 15) && (kt + 63 > qw - WIN);
    if (!active) continue;
    const bool need_c = (kt + 63 > qw);            // causal boundary tile
    const bool need_l = (kt + WIN <= qw + 15);     // lower-window boundary

    f32x4 st4[4];
    __builtin_amdgcn_s_setprio(1);
#pragma unroll
    for (int nt = 0; nt < 4; ++nt) {
      f32x4 acc = (f32x4){0.f, 0.f, 0.f, 0.f};
#pragma unroll
      for (int kb = 0; kb < 4; ++kb) {
        bf16x8 kf = *(const bf16x8*)&Ks[(nt * 16 + l16) * KS_STRIDE + kb * 32 + quad * 8];
        acc = __builtin_amdgcn_mfma_f32_16x16x32_bf16(kf, qf[kb], acc, 0, 0, 0);
      }
      st4[nt] = acc;
    }
    __builtin_amdgcn_s_setprio(0);

    if (need_c || need_l) {
#pragma unroll
      for (int nt = 0; nt < 4; ++nt)
#pragma unroll
        for (int r = 0; r < 4; ++r) {
          const int key = kt + nt * 16 + quad * 4 + r;
          const bool ok = (!need_c || key <= q) && (!need_l || key > q - WIN);
          st4[nt][r] = ok ? st4[nt][r] : -__builtin_inff();
        }
    }

    float mx = -__builtin_inff();
#pragma unroll
    for (int nt = 0; nt < 4; ++nt)
#pragma unroll
      for (int r = 0; r < 4; ++r) mx = fmaxf(mx, st4[nt][r]);
    mx = fmaxf(mx, __shfl_xor(mx, 16, 64));
    mx = fmaxf(mx, __shfl_xor(mx, 32, 64));

    // T13 defer-max: keep stale max unless some row grew by >8 (log2 units).
    float msub;
    if (!__all(mx - m_run <= 8.f)) {   // NaN(-inf - -inf) -> grow path
      const float mnew = fmaxf(m_run, mx);
      msub = (mnew == -__builtin_inff()) ? 0.f : mnew;
      const float alpha = __builtin_amdgcn_exp2f(m_run - msub);
      l_run *= alpha;
#pragma unroll
      for (int dt = 0; dt < 8; ++dt) o[dt] *= alpha;
      m_run = mnew;
    } else {
      msub = m_run;
    }

    float psum = 0.f;
    s16x4 pb[4];
#pragma unroll
    for (int nt = 0; nt < 4; ++nt)
#pragma unroll
      for (int r = 0; r < 4; ++r) {
        const float pv = __builtin_amdgcn_exp2f(st4[nt][r] - msub);
        psum += pv;
        union { __bf16 hh; short ss; } u;
        u.hh = (bf16)pv;
        pb[nt][r] = u.ss;
      }
    psum += __shfl_xor(psum, 16, 64);
    psum += __shfl_xor(psum, 32, 64);
    l_run += psum;

    __builtin_amdgcn_s_setprio(1);
#pragma unroll
    for (int dt = 0; dt < 8; ++dt)
#pragma unroll
      for (int nt = 0; nt < 4; ++nt) {
        s16x4 vf = *(const s16x4*)&Vt[(dt * 16 + l16) * VT_STRIDE + nt * 16 + quad * 4];
        o[dt] = __builtin_amdgcn_mfma_f32_16x16x16bf16_1k(vf, pb[nt], o[dt], 0, 0, 0);
      }
    __builtin_amdgcn_s_setprio(0);
  }

  const float inv = 1.f / l_run;
  __syncthreads();   // all LDS consumers done; reuse as output stage
#pragma unroll
  for (int dt = 0; dt < 8; ++dt) {
    bf16x4 t;
#pragma unroll
    for (int r = 0; r < 4; ++r) t[r] = (bf16)(o[dt][r] * inv);
    *(bf16x4*)&Os[(wave * 16 + l16) * KS_STRIDE + dt * 16 + quad * 4] = t;
  }
  __syncthreads();
#pragma unroll
  for (int it = 0; it < 4; ++it) {
    const int idx = tid + it * 512;
    const int row = idx >> 4, chunk = idx & 15;
    bf16x8 v = *(const bf16x8*)&Os[row * KS_STRIDE + chunk * 8];
    *(bf16x8*)(Og + (size_t)(tok0 + q0 + row) * (NH_Q * HD_) + h * HD_ + chunk * 8) = v;
  }
}

// ---------------- launcher ----------------
extern "C" void kernel_launch(void* const* d_in, const int* in_sizes, int n_in,
                              void* d_out, int out_size, void* d_ws, size_t ws_size,
                              hipStream_t stream) {
  const float* hs = (const float*)d_in[0];
  const float* Wq = (const float*)d_in[1];
  const float* Wk = (const float*)d_in[2];
  const float* Wv = (const float*)d_in[3];
  const float* Wo = (const float*)d_in[4];
  float* out = (float*)d_out;

  char* w = (char*)d_ws;
  bf16* hsb = (bf16*)w; w += (size_t)NTOK * 2048 * 2;   // 16.8 MB
  bf16* wqb = (bf16*)w; w += (size_t)2048 * 2048 * 2;   //  8.4 MB
  bf16* wkb = (bf16*)w; w += (size_t)512 * 2048 * 2;    //  2.1 MB
  bf16* wvb = (bf16*)w; w += (size_t)512 * 2048 * 2;    //  2.1 MB
  bf16* wob = (bf16*)w; w += (size_t)2048 * 2048 * 2;   //  8.4 MB
  bf16* qb  = (bf16*)w; w += (size_t)NTOK * 2048 * 2;   // 16.8 MB
  bf16* kb  = (bf16*)w; w += (size_t)NTOK * 512 * 2;    //  4.2 MB
  bf16* vtb = (bf16*)w; w += (size_t)NTOK * 512 * 2;    //  4.2 MB
  bf16* ab  = hsb;  // alias: hs_bf16 dead after QKV GEMM

  cvt_all<<<18874368 / 1024, 256, 0, stream>>>(hs, Wq, Wk, Wv, Wo,
                                               hsb, wqb, wkb, wvb, wob);

  gemm_qkv11<<<dim3(16, 16), 512, 0, stream>>>(hsb, wqb, wkb, wvb,
                                               qb, kb, vtb);

  attn_kernel<<<dim3(S_LEN / 128, NH_Q, 2), 512, 0, stream>>>(qb, kb, vtb, ab);

  gemm_out8<<<dim3(16, 16), 512, 0, stream>>>(ab, wob, out);
}